// Round 9
// baseline (149.281 us; speedup 1.0000x reference)
//
#include <hip/hip_runtime.h>
#include <stdint.h>

#define N2 2048
#define NN (2048UL * 2048UL)

typedef __attribute__((ext_vector_type(8))) short short8;
typedef __attribute__((ext_vector_type(8))) unsigned short u16x8;
typedef __attribute__((ext_vector_type(4))) float f32x4;

__device__ __forceinline__ unsigned short f2bf(float f) {
    unsigned int u = __float_as_uint(f);
    u += 0x7FFFu + ((u >> 16) & 1u);   // round-to-nearest-even
    return (unsigned short)(u >> 16);
}
__device__ __forceinline__ float bf2f(unsigned short u) {
    return __uint_as_float((unsigned int)u << 16);
}

__device__ __forceinline__ void gload16(const void* g, void* l) {
    __builtin_amdgcn_global_load_lds(
        (const __attribute__((address_space(1))) unsigned int*)g,
        (__attribute__((address_space(3))) unsigned int*)l, 16, 0, 0);
}

// ---------------------------------------------------------------------------
// combine: HA[c][n][m]  = sum_e s1[c][e] A[e][n][m]   (bf16, row-major)
//          HBt[c][m][n] = sum_e s2[c][e] A[e][n][m]   (bf16, transposed)
//          HB2t[c][m][n]= sum_e s3[c][e] A[e][n][m]   (bf16, transposed)
//          PB2[c][bx][n] = partial row sums of HB2-combine over this m-block
// (512,4): round-7 configuration — (512,2) halved occupancy and regressed.
// ---------------------------------------------------------------------------
__global__ __launch_bounds__(512, 4) void combine_kernel(
    const float* __restrict__ A, const float* __restrict__ w01,
    const float* __restrict__ w02, const float* __restrict__ w11,
    unsigned short* __restrict__ HA, unsigned short* __restrict__ HBt,
    unsigned short* __restrict__ HB2t, float* __restrict__ PB2) {
    __shared__ float s[3][2][5];
    __shared__ float tile[2][64][68];   // 34.8 KB
    const int tid = threadIdx.x;
    if (tid < 6) {
        const int wi = tid >> 1, c = tid & 1;
        const float* w = (wi == 0 ? w01 : (wi == 1 ? w02 : w11)) + c * 5;
        float mx = w[0];
        for (int e = 1; e < 5; e++) mx = fmaxf(mx, w[e]);
        float ex[5], sum = 0.f;
        for (int e = 0; e < 5; e++) { ex[e] = expf(w[e] - mx); sum += ex[e]; }
        for (int e = 0; e < 5; e++) s[wi][c][e] = ex[e] / sum;
    }
    __syncthreads();

    const int nr  = tid >> 3;          // 0..63
    const int mc8 = (tid & 7) * 8;     // 0..56
    const size_t gn = (size_t)blockIdx.y * 64 + nr;
    const size_t gm = (size_t)blockIdx.x * 64 + mc8;
    const float* ap = A + gn * N2 + gm;

    float4 av[10];
    #pragma unroll
    for (int e = 0; e < 5; e++) {
        av[2 * e]     = *(const float4*)(ap + (size_t)e * NN);
        av[2 * e + 1] = *(const float4*)(ap + (size_t)e * NN + 4);
    }

    float acc[6][8] = {};
    #pragma unroll
    for (int e = 0; e < 5; e++) {
        const float a[8] = {av[2*e].x, av[2*e].y, av[2*e].z, av[2*e].w,
                            av[2*e+1].x, av[2*e+1].y, av[2*e+1].z, av[2*e+1].w};
        #pragma unroll
        for (int c = 0; c < 2; c++) {
            const float q0 = s[0][c][e], q1 = s[1][c][e], q2 = s[2][c][e];
            #pragma unroll
            for (int i = 0; i < 8; i++) {
                acc[c][i]     += q0 * a[i];
                acc[2 + c][i] += q1 * a[i];
                acc[4 + c][i] += q2 * a[i];
            }
        }
    }

    #pragma unroll
    for (int c = 0; c < 2; c++) {
        u16x8 v;
        #pragma unroll
        for (int i = 0; i < 8; i++) v[i] = f2bf(acc[c][i]);
        *(u16x8*)&HA[(size_t)c * NN + gn * N2 + gm] = v;
    }

    #pragma unroll
    for (int c = 0; c < 2; c++) {
        float v = 0.f;
        #pragma unroll
        for (int i = 0; i < 8; i++) v += acc[4 + c][i];
        v += __shfl_xor(v, 1);
        v += __shfl_xor(v, 2);
        v += __shfl_xor(v, 4);
        if ((tid & 7) == 0)
            PB2[(size_t)c * 32 * 2048 + (size_t)blockIdx.x * 2048 + gn] = v;
    }

    #pragma unroll
    for (int rr = 0; rr < 2; rr++) {
        __syncthreads();
        #pragma unroll
        for (int rl = 0; rl < 2; rl++)
            #pragma unroll
            for (int i = 0; i < 8; i++)
                tile[rl][mc8 + i][nr] = acc[2 + rr * 2 + rl][i];
        __syncthreads();
        #pragma unroll
        for (int rl = 0; rl < 2; rl++) {
            const float4 t0 = *(const float4*)&tile[rl][nr][mc8];
            const float4 t1 = *(const float4*)&tile[rl][nr][mc8 + 4];
            u16x8 v;
            v[0] = f2bf(t0.x); v[1] = f2bf(t0.y); v[2] = f2bf(t0.z); v[3] = f2bf(t0.w);
            v[4] = f2bf(t1.x); v[5] = f2bf(t1.y); v[6] = f2bf(t1.z); v[7] = f2bf(t1.w);
            unsigned short* dst = (rr == 0 ? HBt : HB2t) + (size_t)rl * NN
                + ((size_t)blockIdx.x * 64 + nr) * N2
                + (size_t)blockIdx.y * 64 + mc8;
            *(u16x8*)dst = v;
        }
    }
}

// ---------------------------------------------------------------------------
// b2sum[c][n] = sum_bx PB2[c][bx][n]
// ---------------------------------------------------------------------------
__global__ __launch_bounds__(256) void b2fold_kernel(
    const float* __restrict__ PB2, float* __restrict__ b2sum) {
    const int r = blockIdx.x * 256 + threadIdx.x;   // c*2048 + n
    const int c = r >> 11, n = r & 2047;
    float sum = 0.f;
    #pragma unroll
    for (int bx = 0; bx < 32; bx++) sum += PB2[c * 65536 + bx * 2048 + n];
    b2sum[r] = sum;
}

// ---------------------------------------------------------------------------
// bf16 GEMM, B^T input: C[c] = A[c] @ B[c].
// 256x128 tile, BK=64, 8 waves (4Mx2N), per-wave 64x64 (4x4 frags 16x16x32).
// 3 LDS buffers (144KB), 2-tile-ahead prefetch, 1 barrier + counted waits
// per K-tile. Plain blockIdx (XCD swizzle reverted: inputs are L3-fit,
// where swizzle measures -2%).
// MODE 0: bf16 C store + partial row sums P + b2sum-weighted partials Pw.
// MODE 1: fp32 C store scaled by sfac[row] (final H).
// ---------------------------------------------------------------------------
#define GBM 256
#define GBN 128
#define GBK 64
#define BUF_SHORTS 24576   // 48KB per buffer

template <int MODE>
__global__ __launch_bounds__(512, 2) void gemm_bt4(
    const unsigned short* __restrict__ A, const unsigned short* __restrict__ Bt,
    void* __restrict__ Cout, float* __restrict__ P, float* __restrict__ Pw,
    const float* __restrict__ b2sum, const float* __restrict__ sfac) {
    __shared__ unsigned short lds[3 * BUF_SHORTS];   // 144 KB

    const int tid  = threadIdx.x;
    const int wave = tid >> 6, lane = tid & 63;
    const int wm = wave >> 1, wn = wave & 1;
    const int wr = wm * 64;             // 0,64,128,192
    const int wc = wn * 64;             // 0,64
    const int l16 = lane & 15, lhi = lane >> 4;
    const int lsw = l16 & 7;            // row-dependent swizzle bits

    const int bx = blockIdx.x, by = blockIdx.y, bz = blockIdx.z;
    const int brow = by * GBM;
    const int bcol = bx * GBN;
    const size_t cz = (size_t)bz * NN;
    const unsigned short* Ab  = A  + cz + (size_t)brow * N2;
    const unsigned short* Btb = Bt + cz + (size_t)bcol * N2;

    // 6 stage loads per thread, FIFO order = consumption order.
    const unsigned short* src[6];
    #pragma unroll
    for (int L = 0; L < 6; L++) {
        const int g = L * 512 + tid;
        int r, s;
        const unsigned short* basep;
        if (g < 1024) {                       // A half0: rows (r&63)<32
            r = (g >> 8) * 64 + ((g >> 3) & 31);
            s = (g & 7) ^ (r & 7);
            basep = Ab;
        } else if (g < 2048) {                // B
            const int h = g - 1024;
            r = h >> 3;
            s = (h & 7) ^ (r & 7);
            basep = Btb;
        } else {                              // A half1: rows (r&63)>=32
            const int h = g - 2048;
            r = (h >> 8) * 64 + 32 + ((h >> 3) & 31);
            s = (h & 7) ^ (r & 7);
            basep = Ab;
        }
        src[L] = basep + (size_t)r * N2 + s * 8;
    }

    #define STAGE6(buf, k0)                                                   \
        do {                                                                  \
            unsigned short* dst = lds + (buf) * BUF_SHORTS + tid * 8;         \
            _Pragma("unroll")                                                 \
            for (int i = 0; i < 6; i++)                                       \
                gload16(src[i] + (k0), dst + i * 4096);                       \
        } while (0)

    f32x4 acc[4][4] = {};

    STAGE6(0, 0);
    STAGE6(1, GBK);

    const int nt = N2 / GBK;   // 32
    for (int t = 0; t < nt; ++t) {
        const unsigned short* base = lds + (t % 3) * BUF_SHORTS;

        if (t < nt - 1) asm volatile("s_waitcnt vmcnt(6)" ::: "memory");
        else            asm volatile("s_waitcnt vmcnt(0)" ::: "memory");
        __builtin_amdgcn_s_barrier();          // tile t fully staged, all waves
        __builtin_amdgcn_sched_barrier(0);

        short8 af0[2][2], bfr[4][2], af1[2][2];
        // group 1: 12 reads (A-half0 frags + B frags)
        #pragma unroll
        for (int m = 0; m < 2; m++) {
            const unsigned short* rowp = base + wm * 2048 + (m * 16 + l16) * 64;
            #pragma unroll
            for (int ks = 0; ks < 2; ks++)
                af0[m][ks] = *(const short8*)(rowp + (((ks * 4 + lhi) ^ lsw) * 8));
        }
        #pragma unroll
        for (int n = 0; n < 4; n++) {
            const unsigned short* rowp = base + 8192 + (wc + n * 16 + l16) * 64;
            #pragma unroll
            for (int ks = 0; ks < 2; ks++)
                bfr[n][ks] = *(const short8*)(rowp + (((ks * 4 + lhi) ^ lsw) * 8));
        }
        __builtin_amdgcn_sched_barrier(0);     // group fence for lgkmcnt(4)
        // group 2: 4 reads (A-half1 frags) + prefetch tile t+2
        #pragma unroll
        for (int m = 0; m < 2; m++) {
            const unsigned short* rowp = base + 16384 + wm * 2048 + (m * 16 + l16) * 64;
            #pragma unroll
            for (int ks = 0; ks < 2; ks++)
                af1[m][ks] = *(const short8*)(rowp + (((ks * 4 + lhi) ^ lsw) * 8));
        }
        if (t + 2 < nt) STAGE6((t + 2) % 3, (t + 2) * GBK);

        asm volatile("s_waitcnt lgkmcnt(4)" ::: "memory");  // group 1 complete
        __builtin_amdgcn_sched_barrier(0);
        __builtin_amdgcn_s_setprio(1);
        #pragma unroll
        for (int ks = 0; ks < 2; ks++)
            #pragma unroll
            for (int m = 0; m < 2; m++)
                #pragma unroll
                for (int n = 0; n < 4; n++)
                    acc[m][n] = __builtin_amdgcn_mfma_f32_16x16x32_bf16(
                        af0[m][ks], bfr[n][ks], acc[m][n], 0, 0, 0);
        __builtin_amdgcn_s_setprio(0);

        asm volatile("s_waitcnt lgkmcnt(0)" ::: "memory");  // group 2 complete
        __builtin_amdgcn_sched_barrier(0);
        __builtin_amdgcn_s_setprio(1);
        #pragma unroll
        for (int ks = 0; ks < 2; ks++)
            #pragma unroll
            for (int m = 0; m < 2; m++)
                #pragma unroll
                for (int n = 0; n < 4; n++)
                    acc[2 + m][n] = __builtin_amdgcn_mfma_f32_16x16x32_bf16(
                        af1[m][ks], bfr[n][ks], acc[2 + m][n], 0, 0, 0);
        __builtin_amdgcn_s_setprio(0);
    }
    #undef STAGE6

    if constexpr (MODE == 0) {
        unsigned short* Cb = (unsigned short*)Cout + cz + (size_t)brow * N2 + bcol;
        #pragma unroll
        for (int m = 0; m < 4; m++) {
            const int r0 = wr + m * 16 + lhi * 4;
            #pragma unroll
            for (int n = 0; n < 4; n++) {
                const int c0 = wc + n * 16 + l16;
                #pragma unroll
                for (int j = 0; j < 4; j++)
                    Cb[(size_t)(r0 + j) * N2 + c0] = f2bf(acc[m][n][j]);
            }
        }
        // weighted cols for Pw: lane covers col wc+n*16+l16
        float b2w[4];
        #pragma unroll
        for (int n = 0; n < 4; n++)
            b2w[n] = b2sum[bz * 2048 + bcol + wc + n * 16 + l16];

        const size_t pb = (size_t)(bx * 2 + wn) * 4096
                        + (size_t)bz * 2048 + brow + wr;
        #pragma unroll
        for (int m = 0; m < 4; m++)
            #pragma unroll
            for (int j = 0; j < 4; j++) {
                float ps = acc[m][0][j] + acc[m][1][j] + acc[m][2][j] + acc[m][3][j];
                float pw = acc[m][0][j] * b2w[0] + acc[m][1][j] * b2w[1]
                         + acc[m][2][j] * b2w[2] + acc[m][3][j] * b2w[3];
                ps += __shfl_xor(ps, 1); pw += __shfl_xor(pw, 1);
                ps += __shfl_xor(ps, 2); pw += __shfl_xor(pw, 2);
                ps += __shfl_xor(ps, 4); pw += __shfl_xor(pw, 4);
                ps += __shfl_xor(ps, 8); pw += __shfl_xor(pw, 8);
                if (l16 == 0) {
                    P [pb + m * 16 + lhi * 4 + j] = ps;
                    Pw[pb + m * 16 + lhi * 4 + j] = pw;
                }
            }
    } else {
        float* Cb = (float*)Cout + cz + (size_t)brow * N2 + bcol;
        float sf[4][4];
        #pragma unroll
        for (int m = 0; m < 4; m++)
            #pragma unroll
            for (int j = 0; j < 4; j++)
                sf[m][j] = sfac[bz * 2048 + brow + wr + m * 16 + lhi * 4 + j];
        #pragma unroll
        for (int m = 0; m < 4; m++) {
            const int r0 = wr + m * 16 + lhi * 4;
            #pragma unroll
            for (int n = 0; n < 4; n++) {
                const int c0 = wc + n * 16 + l16;
                #pragma unroll
                for (int j = 0; j < 4; j++)
                    Cb[(size_t)(r0 + j) * N2 + c0] = acc[m][n][j] * sf[m][j];
            }
        }
    }
}

// ---------------------------------------------------------------------------
// sfac[r]: s0 = sum_cb P[cb][r]; d0 = rsqrt(s0) (guard)
//          deg1 = d0 * sum_cb Pw[cb][r]; sfac = d0 * rsqrt(deg1) (guard)
// ---------------------------------------------------------------------------
__global__ __launch_bounds__(256) void sfac2_kernel(
    const float* __restrict__ P, const float* __restrict__ Pw,
    float* __restrict__ sfac) {
    const int r = blockIdx.x * 256 + threadIdx.x;
    float s0 = 0.f, s1 = 0.f;
    #pragma unroll
    for (int cb = 0; cb < 32; cb++) {
        s0 += P [cb * 4096 + r];
        s1 += Pw[cb * 4096 + r];
    }
    const float d0 = s0 > 0.f ? rsqrtf(s0) : 0.f;
    const float deg1 = d0 * s1;
    sfac[r] = d0 * (deg1 > 0.f ? rsqrtf(deg1) : 0.f);
}

// ---------------------------------------------------------------------------
// head: 64 blocks x 8 targets.
// ---------------------------------------------------------------------------
__global__ __launch_bounds__(256) void head_kernel(
    const float* __restrict__ X, const float* __restrict__ gcn_w,
    const float* __restrict__ gcn_b, const float* __restrict__ lin_w,
    const float* __restrict__ lin_b, const int* __restrict__ tx,
    float* __restrict__ y) {
    __shared__ float xr[8][512];    // 16 KB
    __shared__ float xk[8][132];    // padded
    __shared__ int trg[8];
    const int tid = threadIdx.x, b = blockIdx.x;
    if (tid < 8) trg[tid] = tx[b * 8 + tid];
    __syncthreads();
    #pragma unroll
    for (int q = 0; q < 4; q++) {
        const int idx = q * 1024 + tid * 4;
        const int t = idx >> 9, col = idx & 511;
        *(float4*)&xr[t][col] = *(const float4*)&X[(size_t)trg[t] * 512 + col];
    }
    __syncthreads();
    const int k = tid & 127, tp = tid >> 7;
    const float* wrp = gcn_w + (size_t)k * 512;
    float d[4] = {0.f, 0.f, 0.f, 0.f};
    for (int i = 0; i < 512; i += 4) {
        const float4 wv = *(const float4*)&wrp[i];
        #pragma unroll
        for (int tt = 0; tt < 4; tt++) {
            const float* xp = xr[tp * 4 + tt];
            d[tt] += xp[i] * wv.x + xp[i+1] * wv.y + xp[i+2] * wv.z + xp[i+3] * wv.w;
        }
    }
    const float gb = gcn_b[k];
    #pragma unroll
    for (int tt = 0; tt < 4; tt++) xk[tp * 4 + tt][k] = fmaxf(d[tt] + gb, 0.f);
    __syncthreads();
    if (tid < 64) {
        const int t = tid >> 3, o = tid & 7;
        float a = lin_b[o];
        const float* lw = lin_w + o * 256;
        for (int kk = 0; kk < 128; kk++)
            a += xk[t][kk] * (lw[kk] + lw[128 + kk]);
        y[(size_t)(b * 8 + t) * 8 + o] = a;
    }
}

__global__ void wsoft_kernel(const float* __restrict__ w01,
                             const float* __restrict__ w02,
                             const float* __restrict__ w11,
                             float* __restrict__ out) {
    const int tid = threadIdx.x;
    if (tid < 6) {
        const int wi = tid >> 1, c = tid & 1;
        const float* w = (wi == 0 ? w01 : (wi == 1 ? w02 : w11)) + c * 5;
        float mx = w[0];
        for (int e = 1; e < 5; e++) mx = fmaxf(mx, w[e]);
        float ex[5], sum = 0.f;
        for (int e = 0; e < 5; e++) { ex[e] = expf(w[e] - mx); sum += ex[e]; }
        for (int e = 0; e < 5; e++) out[tid * 5 + e] = ex[e] / sum;
    }
}

// ---------------------------------------------------------------------------
extern "C" void kernel_launch(void* const* d_in, const int* in_sizes, int n_in,
                              void* d_out, int out_size, void* d_ws, size_t ws_size,
                              hipStream_t stream) {
    const float* A     = (const float*)d_in[0];
    const float* X     = (const float*)d_in[1];
    const float* w01   = (const float*)d_in[2];
    const float* w02   = (const float*)d_in[3];
    const float* w11   = (const float*)d_in[4];
    const float* gcn_w = (const float*)d_in[5];
    const float* gcn_b = (const float*)d_in[6];
    const float* lin_w = (const float*)d_in[7];
    const float* lin_b = (const float*)d_in[8];
    const int*   tx    = (const int*)d_in[9];

    float* out  = (float*)d_out;
    float* y    = out;                 // [512, 8]
    float* allw = out + 4096;          // [3, 2, 5]
    float* H    = out + 4126;          // [2, 2048, 2048] fp32 final output

    unsigned short* HA   = (unsigned short*)d_ws;       // [2,N,N] bf16
    unsigned short* HBt  = HA + 2 * NN;                 // [2,N,N] bf16 (B^T)
    unsigned short* HB2t = HBt + 2 * NN;                // [2,N,N] bf16 (B^T)
    unsigned short* C0   = HB2t + 2 * NN;               // [2,N,N] bf16 layer-0 product
    float* P     = (float*)(C0 + 2 * NN);               // [32][4096] partials
    float* Pw    = P + 32 * 4096;                       // [32][4096] weighted
    float* PB2   = Pw + 32 * 4096;                      // [2][32][2048]
    float* b2sum = PB2 + 2 * 32 * 2048;                 // [4096]
    float* sfac  = b2sum + 4096;                        // [4096]

    combine_kernel<<<dim3(32, 32), 512, 0, stream>>>(A, w01, w02, w11,
                                                     HA, HBt, HB2t, PB2);
    b2fold_kernel<<<16, 256, 0, stream>>>(PB2, b2sum);
    gemm_bt4<0><<<dim3(16, 8, 2), 512, 0, stream>>>(HA, HBt, C0, P, Pw, b2sum, nullptr);
    sfac2_kernel<<<16, 256, 0, stream>>>(P, Pw, sfac);
    gemm_bt4<1><<<dim3(16, 8, 2), 512, 0, stream>>>(C0, HB2t, H, nullptr, nullptr, nullptr, sfac);
    head_kernel<<<64, 256, 0, stream>>>(X, gcn_w, gcn_b, lin_w, lin_b, tx, y);
    wsoft_kernel<<<1, 64, 0, stream>>>(w01, w02, w11, allw);
}

// Round 10
// 132.713 us; speedup vs baseline: 1.1248x; 1.1248x over previous
//
#include <hip/hip_runtime.h>
#include <stdint.h>

#define N2 2048
#define NN (2048UL * 2048UL)

typedef __attribute__((ext_vector_type(8))) short short8;
typedef __attribute__((ext_vector_type(8))) unsigned short u16x8;
typedef __attribute__((ext_vector_type(4))) float f32x4;

__device__ __forceinline__ unsigned short f2bf(float f) {
    unsigned int u = __float_as_uint(f);
    u += 0x7FFFu + ((u >> 16) & 1u);   // round-to-nearest-even
    return (unsigned short)(u >> 16);
}
__device__ __forceinline__ float bf2f(unsigned short u) {
    return __uint_as_float((unsigned int)u << 16);
}

__device__ __forceinline__ void gload16(const void* g, void* l) {
    __builtin_amdgcn_global_load_lds(
        (const __attribute__((address_space(1))) unsigned int*)g,
        (__attribute__((address_space(3))) unsigned int*)l, 16, 0, 0);
}

// ---------------------------------------------------------------------------
// combine: HA[c][n][m]  = sum_e s1[c][e] A[e][n][m]   (bf16, row-major)
//          HBt[c][m][n] = sum_e s2[c][e] A[e][n][m]   (bf16, transposed)
//          HB2t[c][m][n]= sum_e s3[c][e] A[e][n][m]   (bf16, transposed)
//          PB2[c][bx][n] = partial row sums of HB2-combine over this m-block
// Round-7 configuration, verbatim.
// ---------------------------------------------------------------------------
__global__ __launch_bounds__(512, 4) void combine_kernel(
    const float* __restrict__ A, const float* __restrict__ w01,
    const float* __restrict__ w02, const float* __restrict__ w11,
    unsigned short* __restrict__ HA, unsigned short* __restrict__ HBt,
    unsigned short* __restrict__ HB2t, float* __restrict__ PB2) {
    __shared__ float s[3][2][5];
    __shared__ float tile[2][64][68];   // 34.8 KB
    const int tid = threadIdx.x;
    if (tid < 6) {
        const int wi = tid >> 1, c = tid & 1;
        const float* w = (wi == 0 ? w01 : (wi == 1 ? w02 : w11)) + c * 5;
        float mx = w[0];
        for (int e = 1; e < 5; e++) mx = fmaxf(mx, w[e]);
        float ex[5], sum = 0.f;
        for (int e = 0; e < 5; e++) { ex[e] = expf(w[e] - mx); sum += ex[e]; }
        for (int e = 0; e < 5; e++) s[wi][c][e] = ex[e] / sum;
    }
    __syncthreads();

    const int nr  = tid >> 3;          // 0..63
    const int mc8 = (tid & 7) * 8;     // 0..56
    const size_t gn = (size_t)blockIdx.y * 64 + nr;
    const size_t gm = (size_t)blockIdx.x * 64 + mc8;
    const float* ap = A + gn * N2 + gm;

    float4 av[10];
    #pragma unroll
    for (int e = 0; e < 5; e++) {
        av[2 * e]     = *(const float4*)(ap + (size_t)e * NN);
        av[2 * e + 1] = *(const float4*)(ap + (size_t)e * NN + 4);
    }

    float acc[6][8] = {};
    #pragma unroll
    for (int e = 0; e < 5; e++) {
        const float a[8] = {av[2*e].x, av[2*e].y, av[2*e].z, av[2*e].w,
                            av[2*e+1].x, av[2*e+1].y, av[2*e+1].z, av[2*e+1].w};
        #pragma unroll
        for (int c = 0; c < 2; c++) {
            const float q0 = s[0][c][e], q1 = s[1][c][e], q2 = s[2][c][e];
            #pragma unroll
            for (int i = 0; i < 8; i++) {
                acc[c][i]     += q0 * a[i];
                acc[2 + c][i] += q1 * a[i];
                acc[4 + c][i] += q2 * a[i];
            }
        }
    }

    #pragma unroll
    for (int c = 0; c < 2; c++) {
        u16x8 v;
        #pragma unroll
        for (int i = 0; i < 8; i++) v[i] = f2bf(acc[c][i]);
        *(u16x8*)&HA[(size_t)c * NN + gn * N2 + gm] = v;
    }

    #pragma unroll
    for (int c = 0; c < 2; c++) {
        float v = 0.f;
        #pragma unroll
        for (int i = 0; i < 8; i++) v += acc[4 + c][i];
        v += __shfl_xor(v, 1);
        v += __shfl_xor(v, 2);
        v += __shfl_xor(v, 4);
        if ((tid & 7) == 0)
            PB2[(size_t)c * 32 * 2048 + (size_t)blockIdx.x * 2048 + gn] = v;
    }

    #pragma unroll
    for (int rr = 0; rr < 2; rr++) {
        __syncthreads();
        #pragma unroll
        for (int rl = 0; rl < 2; rl++)
            #pragma unroll
            for (int i = 0; i < 8; i++)
                tile[rl][mc8 + i][nr] = acc[2 + rr * 2 + rl][i];
        __syncthreads();
        #pragma unroll
        for (int rl = 0; rl < 2; rl++) {
            const float4 t0 = *(const float4*)&tile[rl][nr][mc8];
            const float4 t1 = *(const float4*)&tile[rl][nr][mc8 + 4];
            u16x8 v;
            v[0] = f2bf(t0.x); v[1] = f2bf(t0.y); v[2] = f2bf(t0.z); v[3] = f2bf(t0.w);
            v[4] = f2bf(t1.x); v[5] = f2bf(t1.y); v[6] = f2bf(t1.z); v[7] = f2bf(t1.w);
            unsigned short* dst = (rr == 0 ? HBt : HB2t) + (size_t)rl * NN
                + ((size_t)blockIdx.x * 64 + nr) * N2
                + (size_t)blockIdx.y * 64 + mc8;
            *(u16x8*)dst = v;
        }
    }
}

// ---------------------------------------------------------------------------
// b2sum[c][n] = sum_bx PB2[c][bx][n]
// ---------------------------------------------------------------------------
__global__ __launch_bounds__(256) void b2fold_kernel(
    const float* __restrict__ PB2, float* __restrict__ b2sum) {
    const int r = blockIdx.x * 256 + threadIdx.x;   // c*2048 + n
    const int c = r >> 11, n = r & 2047;
    float sum = 0.f;
    #pragma unroll
    for (int bx = 0; bx < 32; bx++) sum += PB2[c * 65536 + bx * 2048 + n];
    b2sum[r] = sum;
}

// ---------------------------------------------------------------------------
// bf16 GEMM, B^T input: C[c] = A[c] @ B[c].  Round-7 body verbatim.
// 256x128 tile, BK=64, 8 waves (4Mx2N), per-wave 64x64 (4x4 frags 16x16x32).
// 3 LDS buffers (144KB), 2-tile-ahead prefetch, 1 barrier + counted waits
// per K-tile.
// MODE 0: bf16 C store + per-block partial row sums P.
// MODE 1: fp32 C store scaled by sfac[row] (final H).
// ---------------------------------------------------------------------------
#define GBM 256
#define GBN 128
#define GBK 64
#define BUF_SHORTS 24576   // 48KB per buffer

template <int MODE>
__global__ __launch_bounds__(512, 2) void gemm_bt4(
    const unsigned short* __restrict__ A, const unsigned short* __restrict__ Bt,
    void* __restrict__ Cout, float* __restrict__ P,
    const float* __restrict__ sfac) {
    __shared__ unsigned short lds[3 * BUF_SHORTS];   // 144 KB

    const int tid  = threadIdx.x;
    const int wave = tid >> 6, lane = tid & 63;
    const int wm = wave >> 1, wn = wave & 1;
    const int wr = wm * 64;             // 0,64,128,192
    const int wc = wn * 64;             // 0,64
    const int l16 = lane & 15, lhi = lane >> 4;
    const int lsw = l16 & 7;            // row-dependent swizzle bits

    const int brow = blockIdx.y * GBM;
    const int bcol = blockIdx.x * GBN;
    const size_t cz = (size_t)blockIdx.z * NN;
    const unsigned short* Ab  = A  + cz + (size_t)brow * N2;
    const unsigned short* Btb = Bt + cz + (size_t)bcol * N2;

    // 6 stage loads per thread, FIFO order = consumption order.
    const unsigned short* src[6];
    #pragma unroll
    for (int L = 0; L < 6; L++) {
        const int g = L * 512 + tid;
        int r, s;
        const unsigned short* basep;
        if (g < 1024) {                       // A half0: rows (r&63)<32
            r = (g >> 8) * 64 + ((g >> 3) & 31);
            s = (g & 7) ^ (r & 7);
            basep = Ab;
        } else if (g < 2048) {                // B
            const int h = g - 1024;
            r = h >> 3;
            s = (h & 7) ^ (r & 7);
            basep = Btb;
        } else {                              // A half1: rows (r&63)>=32
            const int h = g - 2048;
            r = (h >> 8) * 64 + 32 + ((h >> 3) & 31);
            s = (h & 7) ^ (r & 7);
            basep = Ab;
        }
        src[L] = basep + (size_t)r * N2 + s * 8;
    }

    #define STAGE6(buf, k0)                                                   \
        do {                                                                  \
            unsigned short* dst = lds + (buf) * BUF_SHORTS + tid * 8;         \
            _Pragma("unroll")                                                 \
            for (int i = 0; i < 6; i++)                                       \
                gload16(src[i] + (k0), dst + i * 4096);                       \
        } while (0)

    f32x4 acc[4][4] = {};

    STAGE6(0, 0);
    STAGE6(1, GBK);

    const int nt = N2 / GBK;   // 32
    for (int t = 0; t < nt; ++t) {
        const unsigned short* base = lds + (t % 3) * BUF_SHORTS;

        if (t < nt - 1) asm volatile("s_waitcnt vmcnt(6)" ::: "memory");
        else            asm volatile("s_waitcnt vmcnt(0)" ::: "memory");
        __builtin_amdgcn_s_barrier();          // tile t fully staged, all waves
        __builtin_amdgcn_sched_barrier(0);

        short8 af0[2][2], bfr[4][2], af1[2][2];
        // group 1: 12 reads (A-half0 frags + B frags)
        #pragma unroll
        for (int m = 0; m < 2; m++) {
            const unsigned short* rowp = base + wm * 2048 + (m * 16 + l16) * 64;
            #pragma unroll
            for (int ks = 0; ks < 2; ks++)
                af0[m][ks] = *(const short8*)(rowp + (((ks * 4 + lhi) ^ lsw) * 8));
        }
        #pragma unroll
        for (int n = 0; n < 4; n++) {
            const unsigned short* rowp = base + 8192 + (wc + n * 16 + l16) * 64;
            #pragma unroll
            for (int ks = 0; ks < 2; ks++)
                bfr[n][ks] = *(const short8*)(rowp + (((ks * 4 + lhi) ^ lsw) * 8));
        }
        __builtin_amdgcn_sched_barrier(0);     // group fence for lgkmcnt(4)
        // group 2: 4 reads (A-half1 frags) + prefetch tile t+2
        #pragma unroll
        for (int m = 0; m < 2; m++) {
            const unsigned short* rowp = base + 16384 + wm * 2048 + (m * 16 + l16) * 64;
            #pragma unroll
            for (int ks = 0; ks < 2; ks++)
                af1[m][ks] = *(const short8*)(rowp + (((ks * 4 + lhi) ^ lsw) * 8));
        }
        if (t + 2 < nt) STAGE6((t + 2) % 3, (t + 2) * GBK);

        asm volatile("s_waitcnt lgkmcnt(4)" ::: "memory");  // group 1 complete
        __builtin_amdgcn_sched_barrier(0);
        __builtin_amdgcn_s_setprio(1);
        #pragma unroll
        for (int ks = 0; ks < 2; ks++)
            #pragma unroll
            for (int m = 0; m < 2; m++)
                #pragma unroll
                for (int n = 0; n < 4; n++)
                    acc[m][n] = __builtin_amdgcn_mfma_f32_16x16x32_bf16(
                        af0[m][ks], bfr[n][ks], acc[m][n], 0, 0, 0);
        __builtin_amdgcn_s_setprio(0);

        asm volatile("s_waitcnt lgkmcnt(0)" ::: "memory");  // group 2 complete
        __builtin_amdgcn_sched_barrier(0);
        __builtin_amdgcn_s_setprio(1);
        #pragma unroll
        for (int ks = 0; ks < 2; ks++)
            #pragma unroll
            for (int m = 0; m < 2; m++)
                #pragma unroll
                for (int n = 0; n < 4; n++)
                    acc[2 + m][n] = __builtin_amdgcn_mfma_f32_16x16x32_bf16(
                        af1[m][ks], bfr[n][ks], acc[2 + m][n], 0, 0, 0);
        __builtin_amdgcn_s_setprio(0);
    }
    #undef STAGE6

    if constexpr (MODE == 0) {
        unsigned short* Cb = (unsigned short*)Cout + cz + (size_t)brow * N2 + bcol;
        #pragma unroll
        for (int m = 0; m < 4; m++) {
            const int r0 = wr + m * 16 + lhi * 4;
            #pragma unroll
            for (int n = 0; n < 4; n++) {
                const int c0 = wc + n * 16 + l16;
                #pragma unroll
                for (int j = 0; j < 4; j++)
                    Cb[(size_t)(r0 + j) * N2 + c0] = f2bf(acc[m][n][j]);
            }
        }
        const size_t pb = (size_t)(blockIdx.x * 2 + wn) * 4096
                        + (size_t)blockIdx.z * 2048 + brow + wr;
        #pragma unroll
        for (int m = 0; m < 4; m++)
            #pragma unroll
            for (int j = 0; j < 4; j++) {
                float ps = acc[m][0][j] + acc[m][1][j] + acc[m][2][j] + acc[m][3][j];
                ps += __shfl_xor(ps, 1);
                ps += __shfl_xor(ps, 2);
                ps += __shfl_xor(ps, 4);
                ps += __shfl_xor(ps, 8);
                if (l16 == 0) P[pb + m * 16 + lhi * 4 + j] = ps;
            }
    } else {
        float* Cb = (float*)Cout + cz + (size_t)brow * N2 + bcol;
        float sf[4][4];
        #pragma unroll
        for (int m = 0; m < 4; m++)
            #pragma unroll
            for (int j = 0; j < 4; j++)
                sf[m][j] = sfac[blockIdx.z * 2048 + brow + wr + m * 16 + lhi * 4 + j];
        #pragma unroll
        for (int m = 0; m < 4; m++) {
            const int r0 = wr + m * 16 + lhi * 4;
            #pragma unroll
            for (int n = 0; n < 4; n++) {
                const int c0 = wc + n * 16 + l16;
                #pragma unroll
                for (int j = 0; j < 4; j++)
                    Cb[(size_t)(r0 + j) * N2 + c0] = acc[m][n][j] * sf[m][j];
            }
        }
    }
}

// ---------------------------------------------------------------------------
// merged gemv+dinv: per row r,
//   s0  = sum_cb P[cb][r]           (wave-0 in-register reduce)
//   tot = C0[r,:] . b2sum           (block reduce)
//   d0 = rsqrt(s0); sfac[r] = d0 * rsqrt(d0 * tot)   (guarded)
// ---------------------------------------------------------------------------
__device__ __forceinline__ float block_sum256(float v) {
    #pragma unroll
    for (int off = 32; off; off >>= 1) v += __shfl_xor(v, off, 64);
    __shared__ float wsum[4];
    if ((threadIdx.x & 63) == 0) wsum[threadIdx.x >> 6] = v;
    __syncthreads();
    return wsum[0] + wsum[1] + wsum[2] + wsum[3];
}

__global__ __launch_bounds__(256) void gemv_sfac_kernel(
    const unsigned short* __restrict__ C0, const float* __restrict__ b2sum,
    const float* __restrict__ P, float* __restrict__ sfac) {
    const size_t r = blockIdx.x;               // 0..4095 (c*2048 + row)
    const int tid = threadIdx.x;

    // deg0 from P: wave 0, all 64 lanes active, each loads P[lane&31][r];
    // xor-reduce over {1,2,4,8,16} sums each 32-lane group -> lane 0 = s0.
    float s0 = 0.f;
    if (tid < 64) {
        float v = P[(size_t)(tid & 31) * 4096 + r];
        v += __shfl_xor(v, 1);
        v += __shfl_xor(v, 2);
        v += __shfl_xor(v, 4);
        v += __shfl_xor(v, 8);
        v += __shfl_xor(v, 16);
        s0 = v;
    }

    const unsigned short* row = C0 + r * N2;
    const float* bs = b2sum + ((r >> 11) << 11);
    const int base = tid * 8;
    const u16x8 v = *(const u16x8*)&row[base];
    float sum = 0.f;
    #pragma unroll
    for (int i = 0; i < 8; i++) sum += bf2f(v[i]) * bs[base + i];
    const float tot = block_sum256(sum);
    if (tid == 0) {
        const float d0 = s0 > 0.f ? rsqrtf(s0) : 0.f;
        const float deg1 = d0 * tot;
        sfac[r] = d0 * (deg1 > 0.f ? rsqrtf(deg1) : 0.f);
    }
}

// ---------------------------------------------------------------------------
// head: 64 blocks x 8 targets; block 0 also emits all_Ws (merged wsoft).
// ---------------------------------------------------------------------------
__global__ __launch_bounds__(256) void head_kernel(
    const float* __restrict__ X, const float* __restrict__ gcn_w,
    const float* __restrict__ gcn_b, const float* __restrict__ lin_w,
    const float* __restrict__ lin_b, const int* __restrict__ tx,
    const float* __restrict__ w01, const float* __restrict__ w02,
    const float* __restrict__ w11,
    float* __restrict__ y, float* __restrict__ allw) {
    __shared__ float xr[8][512];    // 16 KB
    __shared__ float xk[8][132];    // padded
    __shared__ int trg[8];
    const int tid = threadIdx.x, b = blockIdx.x;
    if (tid < 8) trg[tid] = tx[b * 8 + tid];
    __syncthreads();
    #pragma unroll
    for (int q = 0; q < 4; q++) {
        const int idx = q * 1024 + tid * 4;
        const int t = idx >> 9, col = idx & 511;
        *(float4*)&xr[t][col] = *(const float4*)&X[(size_t)trg[t] * 512 + col];
    }
    __syncthreads();
    const int k = tid & 127, tp = tid >> 7;
    const float* wrp = gcn_w + (size_t)k * 512;
    float d[4] = {0.f, 0.f, 0.f, 0.f};
    for (int i = 0; i < 512; i += 4) {
        const float4 wv = *(const float4*)&wrp[i];
        #pragma unroll
        for (int tt = 0; tt < 4; tt++) {
            const float* xp = xr[tp * 4 + tt];
            d[tt] += xp[i] * wv.x + xp[i+1] * wv.y + xp[i+2] * wv.z + xp[i+3] * wv.w;
        }
    }
    const float gb = gcn_b[k];
    #pragma unroll
    for (int tt = 0; tt < 4; tt++) xk[tp * 4 + tt][k] = fmaxf(d[tt] + gb, 0.f);
    __syncthreads();
    if (tid < 64) {
        const int t = tid >> 3, o = tid & 7;
        float a = lin_b[o];
        const float* lw = lin_w + o * 256;
        for (int kk = 0; kk < 128; kk++)
            a += xk[t][kk] * (lw[kk] + lw[128 + kk]);
        y[(size_t)(b * 8 + t) * 8 + o] = a;
    }
    // merged wsoft: block 0, threads 64..69 (independent of shared state)
    if (b == 0 && tid >= 64 && tid < 70) {
        const int t6 = tid - 64;
        const int wi = t6 >> 1, c = t6 & 1;
        const float* w = (wi == 0 ? w01 : (wi == 1 ? w02 : w11)) + c * 5;
        float mx = w[0];
        for (int e = 1; e < 5; e++) mx = fmaxf(mx, w[e]);
        float ex[5], sum = 0.f;
        for (int e = 0; e < 5; e++) { ex[e] = expf(w[e] - mx); sum += ex[e]; }
        for (int e = 0; e < 5; e++) allw[t6 * 5 + e] = ex[e] / sum;
    }
}

// ---------------------------------------------------------------------------
extern "C" void kernel_launch(void* const* d_in, const int* in_sizes, int n_in,
                              void* d_out, int out_size, void* d_ws, size_t ws_size,
                              hipStream_t stream) {
    const float* A     = (const float*)d_in[0];
    const float* X     = (const float*)d_in[1];
    const float* w01   = (const float*)d_in[2];
    const float* w02   = (const float*)d_in[3];
    const float* w11   = (const float*)d_in[4];
    const float* gcn_w = (const float*)d_in[5];
    const float* gcn_b = (const float*)d_in[6];
    const float* lin_w = (const float*)d_in[7];
    const float* lin_b = (const float*)d_in[8];
    const int*   tx    = (const int*)d_in[9];

    float* out  = (float*)d_out;
    float* y    = out;                 // [512, 8]
    float* allw = out + 4096;          // [3, 2, 5]
    float* H    = out + 4126;          // [2, 2048, 2048] fp32 final output

    unsigned short* HA   = (unsigned short*)d_ws;       // [2,N,N] bf16
    unsigned short* HBt  = HA + 2 * NN;                 // [2,N,N] bf16 (B^T)
    unsigned short* HB2t = HBt + 2 * NN;                // [2,N,N] bf16 (B^T)
    unsigned short* C0   = HB2t + 2 * NN;               // [2,N,N] bf16 layer-0 product
    float* P     = (float*)(C0 + 2 * NN);               // [32][4096] partials
    float* PB2   = P + 32 * 4096;                       // [2][32][2048]
    float* b2sum = PB2 + 2 * 32 * 2048;                 // [4096]
    float* sfac  = b2sum + 4096;                        // [4096]

    combine_kernel<<<dim3(32, 32), 512, 0, stream>>>(A, w01, w02, w11,
                                                     HA, HBt, HB2t, PB2);
    b2fold_kernel<<<16, 256, 0, stream>>>(PB2, b2sum);
    gemm_bt4<0><<<dim3(16, 8, 2), 512, 0, stream>>>(HA, HBt, C0, P, nullptr);
    gemv_sfac_kernel<<<4096, 256, 0, stream>>>(C0, b2sum, P, sfac);
    gemm_bt4<1><<<dim3(16, 8, 2), 512, 0, stream>>>(C0, HB2t, H, nullptr, sfac);
    head_kernel<<<64, 256, 0, stream>>>(X, gcn_w, gcn_b, lin_w, lin_b, tx,
                                        w01, w02, w11, y, allw);
}